// Round 1
// baseline (698.668 us; speedup 1.0000x reference)
//
#include <hip/hip_runtime.h>

// Problem dims (fixed by setup_inputs): x[4,2048,4096] f32, W[4096,4096] f32,
// lora_A[16,4096], lora_B[4096,16], sigma[16]. out[4,2048,4096] f32.
// out = x @ (W + SCALING * (B*diag(sigma_masked)) @ A)^T
#define D_DIM 4096
#define R_DIM 16
#define SCALING_F 1.0f          // 16.0/16
#define THRESH 0.01f

#define BM 128
#define BN 128
#define BK 32                   // bf16 elements per K-tile (one MFMA K-step)

typedef __attribute__((ext_vector_type(8))) short short8;   // 8 bf16 = 4 VGPRs
typedef __attribute__((ext_vector_type(4))) float floatx4;  // MFMA C/D

__device__ __forceinline__ unsigned int f2bf(float f) {
  union { float f; unsigned int u; } v; v.f = f;
  unsigned int u = v.u;
  u += 0x7FFFu + ((u >> 16) & 1u);   // round-to-nearest-even
  return u >> 16;
}

// ---------------- prep 1: x fp32 -> bf16 (8 elems/thread) ----------------
__global__ __launch_bounds__(256) void convert_x_kernel(
    const float* __restrict__ x, unsigned int* __restrict__ xb, int n8) {
  int idx = blockIdx.x * 256 + threadIdx.x;
  if (idx >= n8) return;
  const float4* xp = (const float4*)x;
  float4 v0 = xp[2 * idx];
  float4 v1 = xp[2 * idx + 1];
  uint4 o;
  o.x = f2bf(v0.x) | (f2bf(v0.y) << 16);
  o.y = f2bf(v0.z) | (f2bf(v0.w) << 16);
  o.z = f2bf(v1.x) | (f2bf(v1.y) << 16);
  o.w = f2bf(v1.z) | (f2bf(v1.w) << 16);
  ((uint4*)xb)[idx] = o;
}

// ------------- prep 2: W_eff = W + (B*sigma_masked) @ A -> bf16 -------------
// One block = one 1024-quad span = exactly one output row o (4096/4 = 1024).
__global__ __launch_bounds__(256) void build_weff_kernel(
    const float* __restrict__ W, const float* __restrict__ lA,
    const float* __restrict__ lB, const float* __restrict__ sigma,
    unsigned int* __restrict__ wb) {
  __shared__ float Bs[R_DIM];
  int idx = blockIdx.x * 256 + threadIdx.x;  // quad index over 16M/4 elements
  int o  = idx >> 10;                         // row (uniform per block)
  int dq = idx & 1023;                        // which float4 within the row
  if (threadIdx.x < R_DIM) {
    float s = sigma[threadIdx.x];
    s = (fabsf(s) >= THRESH) ? s : 0.0f;
    Bs[threadIdx.x] = lB[o * R_DIM + threadIdx.x] * s * SCALING_F;
  }
  __syncthreads();
  float4 acc = ((const float4*)W)[idx];
#pragma unroll
  for (int r = 0; r < R_DIM; ++r) {
    float b = Bs[r];
    float4 a = ((const float4*)(lA + (size_t)r * D_DIM))[dq];
    acc.x += b * a.x; acc.y += b * a.y; acc.z += b * a.z; acc.w += b * a.w;
  }
  uint2 p;
  p.x = f2bf(acc.x) | (f2bf(acc.y) << 16);
  p.y = f2bf(acc.z) | (f2bf(acc.w) << 16);
  ((uint2*)wb)[idx] = p;
}

// ---------------- GEMM: C[M,N] = A[M,K] * B[N,K]^T (bf16 in, f32 out) -------
// m97 structure: 128x128 tile, 4 waves (2x2), each wave 4x4 of 16x16x32 MFMA,
// global_load_lds width=16 staging, 2-barrier K-loop.
__device__ __forceinline__ void load_lds16(const void* g, void* l) {
  __builtin_amdgcn_global_load_lds(
      (const __attribute__((address_space(1))) void*)g,
      (__attribute__((address_space(3))) void*)l, 16, 0, 0);
}

__global__ __launch_bounds__(256) void gemm_bt_kernel(
    const unsigned short* __restrict__ A,   // x bf16 [M, K]
    const unsigned short* __restrict__ B,   // W_eff bf16 [N, K]
    float* __restrict__ C, int M) {
  // LDS tiles: [row][k] contiguous, row stride 64 B — NO padding
  // (global_load_lds writes wave-uniform base + lane*16).
  __shared__ __align__(16) unsigned short sA[BM * BK];
  __shared__ __align__(16) unsigned short sB[BN * BK];

  const int tid  = threadIdx.x;
  const int lane = tid & 63;
  const int wave = tid >> 6;      // 0..3
  const int wm   = wave >> 1;     // wave row 0..1 (64 rows each)
  const int wn   = wave & 1;      // wave col 0..1
  const int lrow = lane & 15;
  const int lq   = lane >> 4;     // quad 0..3

  const int m0 = blockIdx.y * BM;
  const int n0 = blockIdx.x * BN;

  floatx4 acc[4][4] = {};

  // Staging: tile = 128 rows x 64 B. chunk c (0..7) = 1024 B = 16 rows.
  // Wave w owns chunks 2w, 2w+1. Lane's 16 B: row = c*16 + lane/4,
  // k-elem offset = (lane&3)*8.
  const int c0   = wave * 2;
  const int srow = c0 * 16 + (lane >> 2);
  const int kofs = (lane & 3) * 8;
  const unsigned short* aG0 = A + (size_t)(m0 + srow) * D_DIM + kofs;
  const unsigned short* aG1 = aG0 + (size_t)16 * D_DIM;
  const unsigned short* bG0 = B + (size_t)(n0 + srow) * D_DIM + kofs;
  const unsigned short* bG1 = bG0 + (size_t)16 * D_DIM;
  unsigned short* lA0 = sA + c0 * 512;        // wave-uniform LDS chunk base
  unsigned short* lA1 = lA0 + 512;
  unsigned short* lB0 = sB + c0 * 512;
  unsigned short* lB1 = lB0 + 512;

  // Fragment LDS read offsets (elements): A[m=lane&15][k=lq*8+j]
  const int aOff = (wm * 64 + lrow) * BK + lq * 8;
  const int bOff = (wn * 64 + lrow) * BK + lq * 8;

  for (int k0 = 0; k0 < D_DIM; k0 += BK) {
    load_lds16(aG0 + k0, lA0);
    load_lds16(aG1 + k0, lA1);
    load_lds16(bG0 + k0, lB0);
    load_lds16(bG1 + k0, lB1);
    __syncthreads();   // drains vmcnt(0): LDS tiles complete

    short8 af[4], bf[4];
#pragma unroll
    for (int t = 0; t < 4; ++t) {
      af[t] = *(const short8*)(sA + aOff + t * 16 * BK);
      bf[t] = *(const short8*)(sB + bOff + t * 16 * BK);
    }
#pragma unroll
    for (int i = 0; i < 4; ++i)
#pragma unroll
      for (int j = 0; j < 4; ++j)
        acc[i][j] = __builtin_amdgcn_mfma_f32_16x16x32_bf16(
            af[i], bf[j], acc[i][j], 0, 0, 0);

    __syncthreads();   // all waves done reading before next stage overwrites
  }

  // Epilogue: D[row=(lq*4+rr)][col=lrow] per 16x16 tile.
#pragma unroll
  for (int i = 0; i < 4; ++i) {
    const int row0 = m0 + wm * 64 + i * 16 + lq * 4;
#pragma unroll
    for (int j = 0; j < 4; ++j) {
      const int col = n0 + wn * 64 + j * 16 + lrow;
      float* cp = C + (size_t)row0 * D_DIM + col;
#pragma unroll
      for (int rr = 0; rr < 4; ++rr)
        cp[(size_t)rr * D_DIM] = acc[i][j][rr];
    }
  }
}

extern "C" void kernel_launch(void* const* d_in, const int* in_sizes, int n_in,
                              void* d_out, int out_size, void* d_ws, size_t ws_size,
                              hipStream_t stream) {
  const float* x     = (const float*)d_in[0];  // [M, 4096], M = 8192
  const float* W     = (const float*)d_in[1];  // [4096, 4096]
  const float* lA    = (const float*)d_in[2];  // [16, 4096]
  const float* lB    = (const float*)d_in[3];  // [4096, 16]
  const float* sigma = (const float*)d_in[4];  // [16]
  float* out = (float*)d_out;

  const int M = in_sizes[0] / D_DIM;           // 8192
  // Workspace layout: x_bf16 (M*4096*2 = 64 MB) then W_eff bf16 (32 MB).
  unsigned int* xb = (unsigned int*)d_ws;
  unsigned int* wb = (unsigned int*)((char*)d_ws + (size_t)M * D_DIM * 2);

  const int n8 = in_sizes[0] / 8;              // x octets
  convert_x_kernel<<<(n8 + 255) / 256, 256, 0, stream>>>(x, xb, n8);

  const int wquads = (D_DIM * D_DIM) / 4;      // 4,194,304
  build_weff_kernel<<<wquads / 256, 256, 0, stream>>>(W, lA, lB, sigma, wb);

  dim3 grid(D_DIM / BN, M / BM);               // (32, 64) = 2048 blocks
  gemm_bt_kernel<<<grid, 256, 0, stream>>>(
      (const unsigned short*)xb, (const unsigned short*)wb, out, M);
}

// Round 2
// 562.516 us; speedup vs baseline: 1.2420x; 1.2420x over previous
//
#include <hip/hip_runtime.h>

// Problem dims (fixed by setup_inputs): x[4,2048,4096] f32, W[4096,4096] f32,
// lora_A[16,4096], lora_B[4096,16], sigma[16]. out[4,2048,4096] f32.
// out = x @ (W + SCALING * (B*diag(sigma_masked)) @ A)^T
#define D_DIM 4096
#define R_DIM 16
#define SCALING_F 1.0f          // 16.0/16
#define THRESH 0.01f

#define BM 128
#define BN 128
#define BK 64                   // bf16 elements per K-tile (2 MFMA K-steps)

typedef __attribute__((ext_vector_type(8))) short short8;   // 8 bf16 = 4 VGPRs
typedef __attribute__((ext_vector_type(4))) float floatx4;  // MFMA C/D

__device__ __forceinline__ unsigned int f2bf(float f) {
  union { float f; unsigned int u; } v; v.f = f;
  unsigned int u = v.u;
  u += 0x7FFFu + ((u >> 16) & 1u);   // round-to-nearest-even
  return u >> 16;
}

// ---------------- prep 1: x fp32 -> bf16 (8 elems/thread) ----------------
__global__ __launch_bounds__(256) void convert_x_kernel(
    const float* __restrict__ x, unsigned int* __restrict__ xb, int n8) {
  int idx = blockIdx.x * 256 + threadIdx.x;
  if (idx >= n8) return;
  const float4* xp = (const float4*)x;
  float4 v0 = xp[2 * idx];
  float4 v1 = xp[2 * idx + 1];
  uint4 o;
  o.x = f2bf(v0.x) | (f2bf(v0.y) << 16);
  o.y = f2bf(v0.z) | (f2bf(v0.w) << 16);
  o.z = f2bf(v1.x) | (f2bf(v1.y) << 16);
  o.w = f2bf(v1.z) | (f2bf(v1.w) << 16);
  ((uint4*)xb)[idx] = o;
}

// ------------- prep 2: W_eff = W + (B*sigma_masked) @ A -> bf16 -------------
__global__ __launch_bounds__(256) void build_weff_kernel(
    const float* __restrict__ W, const float* __restrict__ lA,
    const float* __restrict__ lB, const float* __restrict__ sigma,
    unsigned int* __restrict__ wb) {
  __shared__ float Bs[R_DIM];
  int idx = blockIdx.x * 256 + threadIdx.x;  // quad index over 16M/4 elements
  int o  = idx >> 10;                         // row (uniform per block)
  int dq = idx & 1023;                        // which float4 within the row
  if (threadIdx.x < R_DIM) {
    float s = sigma[threadIdx.x];
    s = (fabsf(s) >= THRESH) ? s : 0.0f;
    Bs[threadIdx.x] = lB[o * R_DIM + threadIdx.x] * s * SCALING_F;
  }
  __syncthreads();
  float4 acc = ((const float4*)W)[idx];
#pragma unroll
  for (int r = 0; r < R_DIM; ++r) {
    float b = Bs[r];
    float4 a = ((const float4*)(lA + (size_t)r * D_DIM))[dq];
    acc.x += b * a.x; acc.y += b * a.y; acc.z += b * a.z; acc.w += b * a.w;
  }
  uint2 p;
  p.x = f2bf(acc.x) | (f2bf(acc.y) << 16);
  p.y = f2bf(acc.z) | (f2bf(acc.w) << 16);
  ((uint2*)wb)[idx] = p;
}

// ---------------- GEMM: C[M,N] = A[M,K] * B[N,K]^T (bf16 in, f32 out) -------
// 128x128 tile, 4 waves (2x2), each wave 4x4 of 16x16x32 MFMA.
// BK=64: 32 MFMA + 8 in-flight global_load_lds per wave between barriers.
// LDS layout XOR-swizzled: kgroup g of row r stored at column (g ^ (r&7)).
// Row stride = 128 B = 32 banks, so swizzle makes quad reads 2-way (free);
// unswizzled would be 16-way conflicted. Swizzle costs nothing on staging:
// lane l of global_load_lds just sources kgroup (l&7)^(l>>3) instead of l&7.
__device__ __forceinline__ void load_lds16(const void* g, void* l) {
  __builtin_amdgcn_global_load_lds(
      (const __attribute__((address_space(1))) void*)g,
      (__attribute__((address_space(3))) void*)l, 16, 0, 0);
}

__global__ __launch_bounds__(256) void gemm_bt_kernel(
    const unsigned short* __restrict__ A,   // x bf16 [M, K]
    const unsigned short* __restrict__ B,   // W_eff bf16 [N, K]
    float* __restrict__ C, int M) {
  __shared__ __align__(16) unsigned short sA[BM * BK];  // 16 KB
  __shared__ __align__(16) unsigned short sB[BN * BK];  // 16 KB

  const int tid  = threadIdx.x;
  const int lane = tid & 63;
  const int wave = tid >> 6;      // 0..3
  const int wm   = wave >> 1;     // wave row 0..1 (64 rows each)
  const int wn   = wave & 1;      // wave col 0..1
  const int lrow = lane & 15;
  const int lq   = lane >> 4;     // quad 0..3

  const int m0 = blockIdx.y * BM;
  const int n0 = blockIdx.x * BN;

  floatx4 acc[4][4] = {};

  // Staging: tile = 128 rows x 128 B = 16 chunks of 1 KB (8 rows each).
  // Wave w owns chunks 4w..4w+3 (rows 32w..32w+31) for both A and B.
  // Lane l: LDS dest = chunk_base + l*16 -> (row_local = l>>3, col = l&7);
  // swizzle => global kgroup = (l&7) ^ (l>>3).
  const int srow = lane >> 3;                       // 0..7
  const int kofs = (((lane & 7) ^ srow)) * 8;       // element offset in K-tile
  const unsigned short* aG = A + (size_t)(m0 + wave * 32 + srow) * D_DIM + kofs;
  const unsigned short* bG = B + (size_t)(n0 + wave * 32 + srow) * D_DIM + kofs;
  unsigned short* lAc = sA + wave * 2048;           // 4 chunks * 512 shorts
  unsigned short* lBc = sB + wave * 2048;

  // Fragment read column offsets (shorts): col_s = ((s*4+lq) ^ (lrow&7)) * 8
  const int r7   = lrow & 7;
  const int col0 = (lq ^ r7) * 8;          // K-step s=0
  const int col1 = ((4 | lq) ^ r7) * 8;    // K-step s=1
  // Row base offsets (shorts): (wm*64 + t*16 + lrow) * BK
  const int aRow = (wm * 64 + lrow) * BK;
  const int bRow = (wn * 64 + lrow) * BK;

  for (int k0 = 0; k0 < D_DIM; k0 += BK) {
#pragma unroll
    for (int c = 0; c < 4; ++c) {
      load_lds16(aG + (size_t)c * 8 * D_DIM + k0, lAc + c * 512);
      load_lds16(bG + (size_t)c * 8 * D_DIM + k0, lBc + c * 512);
    }
    __syncthreads();   // drains vmcnt(0): LDS tiles complete

#pragma unroll
    for (int s = 0; s < 2; ++s) {
      const int cs = (s == 0) ? col0 : col1;
      short8 af[4], bf[4];
#pragma unroll
      for (int t = 0; t < 4; ++t) {
        af[t] = *(const short8*)(sA + aRow + t * 16 * BK + cs);
        bf[t] = *(const short8*)(sB + bRow + t * 16 * BK + cs);
      }
#pragma unroll
      for (int i = 0; i < 4; ++i)
#pragma unroll
        for (int j = 0; j < 4; ++j)
          acc[i][j] = __builtin_amdgcn_mfma_f32_16x16x32_bf16(
              af[i], bf[j], acc[i][j], 0, 0, 0);
    }

    __syncthreads();   // all waves done reading before next stage overwrites
  }

  // Epilogue: D[row=(lq*4+rr)][col=lrow] per 16x16 tile.
#pragma unroll
  for (int i = 0; i < 4; ++i) {
    const int row0 = m0 + wm * 64 + i * 16 + lq * 4;
#pragma unroll
    for (int j = 0; j < 4; ++j) {
      const int col = n0 + wn * 64 + j * 16 + lrow;
      float* cp = C + (size_t)row0 * D_DIM + col;
#pragma unroll
      for (int rr = 0; rr < 4; ++rr)
        cp[(size_t)rr * D_DIM] = acc[i][j][rr];
    }
  }
}

extern "C" void kernel_launch(void* const* d_in, const int* in_sizes, int n_in,
                              void* d_out, int out_size, void* d_ws, size_t ws_size,
                              hipStream_t stream) {
  const float* x     = (const float*)d_in[0];  // [M, 4096], M = 8192
  const float* W     = (const float*)d_in[1];  // [4096, 4096]
  const float* lA    = (const float*)d_in[2];  // [16, 4096]
  const float* lB    = (const float*)d_in[3];  // [4096, 16]
  const float* sigma = (const float*)d_in[4];  // [16]
  float* out = (float*)d_out;

  const int M = in_sizes[0] / D_DIM;           // 8192
  // Workspace layout: x_bf16 (M*4096*2 = 64 MB) then W_eff bf16 (32 MB).
  unsigned int* xb = (unsigned int*)d_ws;
  unsigned int* wb = (unsigned int*)((char*)d_ws + (size_t)M * D_DIM * 2);

  const int n8 = in_sizes[0] / 8;              // x octets
  convert_x_kernel<<<(n8 + 255) / 256, 256, 0, stream>>>(x, xb, n8);

  const int wquads = (D_DIM * D_DIM) / 4;      // 4,194,304
  build_weff_kernel<<<wquads / 256, 256, 0, stream>>>(W, lA, lB, sigma, wb);

  dim3 grid(D_DIM / BN, M / BM);               // (32, 64) = 2048 blocks
  gemm_bt_kernel<<<grid, 256, 0, stream>>>(
      (const unsigned short*)xb, (const unsigned short*)wb, out, M);
}